// Round 5
// baseline (61557.861 us; speedup 1.0000x reference)
//
#include <hip/hip_runtime.h>
#include <hip/hip_bf16.h>
#include <math.h>

#define S_LEN 512
#define BATCH 32
#define HID   512
#define G4    2048   // 4*H
#define DIM   300
#define NHEAD 8
#define HDIM  128
#define CH    64     // timesteps per xg chunk
#define NCH   8

typedef __hip_bfloat16 bf16;

// ---------------- workspace layout (float offsets) ----------------
#define OFF_XGC   0ull          //  8,388,608 f  [2 dir][64 slot][2048 n][32 b]
#define OFF_HCAT0 8388608ull    // 16,777,216 f  [32 b][512 s][1024]
#define OFF_HCAT1 25165824ull   // 16,777,216 f  (h0 [16384][300] aliases)
#define OFF_H0    25165824ull
#define OFF_WP    41943040ull   //  3,145,728 f
#define OFF_PB    45088768ull   //      3,072 f
#define OFF_CT    45091840ull   //     32,768 f  [(dir*512+u)*32 + b]
#define OFF_HG    45124608ull   //     65,536 f  [parity][dir][32 b][512 k]
#define OFF_POOL  45190144ull   //     32,768 f
#define OFF_BAR   45222912ull   //      4,096 B barrier state (8 groups x 64 u32)
// group g: arrive slots bar[g*64 + 0..31], flag bar[g*64 + 48]

// ---------------- embedding gather ----------------
__global__ void k_embed(const int* __restrict__ x, const float* __restrict__ emb,
                        float* __restrict__ h0)
{
    int p = blockIdx.x;                 // p = b*512 + s
    int row = x[p];
    const float* src = emb + (size_t)row * DIM;
    float* dst = h0 + (size_t)p * DIM;
    for (int d = threadIdx.x; d < DIM; d += blockDim.x) dst[d] = src[d];
}

// ---------------- chunk input-projection GEMM ----------------
__global__ __launch_bounds__(256) void k_xgc(const float* __restrict__ A, int lda,
    const float* __restrict__ Wf, const float* __restrict__ Wb,
    const float* __restrict__ bihf, const float* __restrict__ bhhf,
    const float* __restrict__ bihb, const float* __restrict__ bhhb,
    float* __restrict__ xgc, int K, int c64)
{
    __shared__ float As[8][128];
    __shared__ float Bs[8][128];
    int tid = threadIdx.x;
    int dir = blockIdx.z;
    int m0 = blockIdx.y * 128, n0 = blockIdx.x * 128;
    const float* W  = dir ? Wb : Wf;
    const float* b1 = dir ? bihb : bihf;
    const float* b2 = dir ? bhhb : bhhf;
    int tx = tid & 15, ty = tid >> 4;

    float acc[8][8];
#pragma unroll
    for (int i = 0; i < 8; i++)
#pragma unroll
        for (int j = 0; j < 8; j++) acc[i][j] = 0.f;

    for (int k0 = 0; k0 < K; k0 += 8) {
#pragma unroll
        for (int e4 = 0; e4 < 4; e4++) {
            int e = tid * 4 + e4;
            int kl = e & 7, ml = e >> 3;
            int kk = k0 + kl;
            int m = m0 + ml;
            int slot = m >> 5, bb = m & 31;
            int s = dir ? (S_LEN - 1 - c64 - slot) : (c64 + slot);
            As[kl][ml] = (kk < K) ? A[((size_t)bb * S_LEN + s) * lda + kk] : 0.f;
            Bs[kl][ml] = (kk < K) ? W[(size_t)(n0 + ml) * K + kk] : 0.f;
        }
        __syncthreads();
#pragma unroll
        for (int k = 0; k < 8; k++) {
            float a[8], b[8];
#pragma unroll
            for (int i = 0; i < 8; i++) a[i] = As[k][ty + 16 * i];
#pragma unroll
            for (int j = 0; j < 8; j++) b[j] = Bs[k][tx + 16 * j];
#pragma unroll
            for (int i = 0; i < 8; i++)
#pragma unroll
                for (int j = 0; j < 8; j++) acc[i][j] += a[i] * b[j];
        }
        __syncthreads();
    }

#pragma unroll
    for (int i = 0; i < 8; i++) {
        int m = m0 + ty + 16 * i;
        int slot = m >> 5, bb = m & 31;
#pragma unroll
        for (int j = 0; j < 8; j++) {
            int n = n0 + tx + 16 * j;
            xgc[(((size_t)dir * CH + slot) * G4 + n) * BATCH + bb] =
                acc[i][j] + b1[n] + b2[n];
        }
    }
}

// ---------------- persistent recurrence: weights in registers ----------------
// 256 WGs = ublk(32) x [dir(2) x bgrp(4)].  gid = bid&7.
// WG: 16 units x 4 gates = 64 rows, 8 batches.  512 thr: ks=tid&31,
// rgrp=tid>>5 (4 rows each).  Weights: 4x4 float4 = 64 VGPR, loaded once.
// Barrier: per-WG release slot -> leader wave-AND poll -> flag; s_sleep backoff.
__global__ __launch_bounds__(512) void k_chunk(const float* __restrict__ xgc,
    const float* __restrict__ Whh_f, const float* __restrict__ Whh_b,
    float* __restrict__ hG, float* __restrict__ cT, float* __restrict__ hcat,
    unsigned int* __restrict__ bar, int c64, int tbase)
{
    __shared__ float Hs[8 * 512];        // [b_local][k]
    __shared__ float gbuf[64][8];        // [row_id][b_local]

    int bid = blockIdx.x;
    int gid = bid & 7;                   // (dir,bgrp) group
    int dir = (gid >> 2) & 1;
    int bgrp = gid & 3;
    int ublk = bid >> 3;                 // 0..31
    const float* Whh = dir ? Whh_b : Whh_f;

    int tid = threadIdx.x;
    int ks = tid & 31;
    int rgrp = tid >> 5;                 // 0..15

    // ---- weights -> registers (coalesced: lanes stride 16B) ----
    float4 w[4][4];
#pragma unroll
    for (int r = 0; r < 4; ++r) {
        int row_id = rgrp * 4 + r;                 // 0..63 ; g = row>>4, ul = row&15
        int g = row_id >> 4, ul = row_id & 15;
        const float* wrow = Whh + (size_t)(g * HID + ublk * 16 + ul) * HID;
#pragma unroll
        for (int q = 0; q < 4; ++q)
            w[r][q] = *(const float4*)(wrow + q * 128 + ks * 4);
    }

    // ---- finisher state (tid<128): (u_local, bl) ----
    int u_local = tid >> 3, bl = tid & 7;
    int b_glob = bgrp * 8 + bl;
    int u_glob = ublk * 16 + u_local;
    size_t ci = ((size_t)dir * HID + u_glob) * BATCH + b_glob;
    float c_reg = 0.f;
    if (tid < 128 && c64 > 0) c_reg = cT[ci];

    unsigned int* slots = bar + gid * 64;

    for (int i = 0; i < CH; ++i) {
        int tt = c64 + i;
        int s_cur = dir ? (S_LEN - 1 - tt) : tt;

        if (i > 0) {   // group barrier: step i-1 h-writes -> step i reads
            unsigned tgt = (unsigned)(tbase + i);
            __syncthreads();
            if (tid == 0)
                __hip_atomic_store(&slots[ublk], tgt,
                                   __ATOMIC_RELEASE, __HIP_MEMORY_SCOPE_AGENT);
            if (ublk == 0) {
                if (tid < 32) {
                    while (__hip_atomic_load(&slots[tid], __ATOMIC_ACQUIRE,
                                             __HIP_MEMORY_SCOPE_AGENT) < tgt)
                        __builtin_amdgcn_s_sleep(8);
                }
                if (tid == 0)
                    __hip_atomic_store(&slots[48], tgt,
                                       __ATOMIC_RELEASE, __HIP_MEMORY_SCOPE_AGENT);
            } else {
                if (tid == 0) {
                    while (__hip_atomic_load(&slots[48], __ATOMIC_ACQUIRE,
                                             __HIP_MEMORY_SCOPE_AGENT) < tgt)
                        __builtin_amdgcn_s_sleep(8);
                }
            }
            __syncthreads();
        }

        // ---- stage h(t-1): global -> LDS, fully packed ----
        if (tt > 0) {
            int pr = (tt & 1) ^ 1;
            int l = tid & 63, bload = tid >> 6;    // 8 b x 64 lanes x 8 floats
            const float* src = hG +
                ((size_t)(pr * 2 + dir) * BATCH + bgrp * 8 + bload) * HID;
            float4 v0 = *(const float4*)(src + l * 4);
            float4 v1 = *(const float4*)(src + 256 + l * 4);
            *(float4*)&Hs[bload * 512 + l * 4] = v0;
            *(float4*)&Hs[bload * 512 + 256 + l * 4] = v1;
        }
        __syncthreads();

        if (tt > 0) {
            float p[32];
#pragma unroll
            for (int j = 0; j < 32; ++j) p[j] = 0.f;
#pragma unroll
            for (int b = 0; b < 8; ++b) {
                const float4* hb = (const float4*)&Hs[b * 512 + ks * 4];
                float4 h0 = hb[0], h1 = hb[32], h2 = hb[64], h3 = hb[96];
#pragma unroll
                for (int r = 0; r < 4; ++r) {
                    p[r * 8 + b] +=
                        w[r][0].x*h0.x + w[r][0].y*h0.y + w[r][0].z*h0.z + w[r][0].w*h0.w +
                        w[r][1].x*h1.x + w[r][1].y*h1.y + w[r][1].z*h1.z + w[r][1].w*h1.w +
                        w[r][2].x*h2.x + w[r][2].y*h2.y + w[r][2].z*h2.z + w[r][2].w*h2.w +
                        w[r][3].x*h3.x + w[r][3].y*h3.y + w[r][3].z*h3.z + w[r][3].w*h3.w;
                }
            }
            // tournament reduce over the 32 ks lanes: 31 shfl, lane -> 1 sum
#pragma unroll
            for (int st = 0; st < 5; ++st) {
                int m = 1 << st;
                int cnt = 16 >> st;
                bool hi = (ks & m) != 0;
#pragma unroll
                for (int j = 0; j < cnt; ++j) {
                    float send = hi ? p[j] : p[j + cnt];
                    float recv = __shfl_xor(send, m);
                    float keep = hi ? p[j + cnt] : p[j];
                    p[j] = keep + recv;
                }
            }
            // lane ks holds sum for partial index brev5(ks) = r*8+b
            int idx = ((ks & 1) << 4) | ((ks & 2) << 2) | (ks & 4) |
                      ((ks & 8) >> 2) | ((ks & 16) >> 4);
            gbuf[rgrp * 4 + (idx >> 3)][idx & 7] = p[0];
        }
        __syncthreads();

        // ---- finisher: gates -> c,h ----
        if (tid < 128) {
            float r0 = 0.f, r1 = 0.f, r2 = 0.f, r3 = 0.f;
            if (tt > 0) {
                r0 = gbuf[0 * 16 + u_local][bl];
                r1 = gbuf[1 * 16 + u_local][bl];
                r2 = gbuf[2 * 16 + u_local][bl];
                r3 = gbuf[3 * 16 + u_local][bl];
            }
            size_t xb = (((size_t)dir * CH + i) * G4) * BATCH + b_glob;
            float gi = r0 + xgc[xb + (size_t)(0 * HID + u_glob) * BATCH];
            float gf = r1 + xgc[xb + (size_t)(1 * HID + u_glob) * BATCH];
            float gg = r2 + xgc[xb + (size_t)(2 * HID + u_glob) * BATCH];
            float go = r3 + xgc[xb + (size_t)(3 * HID + u_glob) * BATCH];
            float si = 1.f / (1.f + expf(-gi));
            float sf = 1.f / (1.f + expf(-gf));
            float so = 1.f / (1.f + expf(-go));
            float cn = sf * c_reg + si * tanhf(gg);
            float hn = so * tanhf(cn);
            c_reg = cn;
            int pw = tt & 1;
            hG[((size_t)(pw * 2 + dir) * BATCH + b_glob) * HID + u_glob] = hn;
            hcat[((size_t)b_glob * S_LEN + s_cur) * 1024 + dir * HID + u_glob] = hn;
        }
    }
    if (tid < 128) cT[ci] = c_reg;
}

// ---------------- pack Wq/Wk/Wv -> Wp[3072][1024] + packed bias ----------------
__global__ void k_pack(const float* __restrict__ Wq, const float* __restrict__ Wk,
                       const float* __restrict__ Wv, const float* __restrict__ bq,
                       const float* __restrict__ bk, const float* __restrict__ bv,
                       float* __restrict__ Wp, float* __restrict__ pb)
{
    size_t i = (size_t)blockIdx.x * 256 + threadIdx.x;
    if (i < 3ull * 1024 * 1024) {
        int tt = (int)(i >> 20);
        int w  = (int)(i & 1048575);
        int n  = w >> 10;      // h*128+e
        int d  = w & 1023;
        int hh = n >> 7, e = n & 127;
        const float* W = (tt == 0) ? Wq : (tt == 1 ? Wk : Wv);
        Wp[i] = W[((size_t)hh * 1024 + d) * 128 + e];
    }
    if (i < 3072) {
        int tt = (int)(i >> 10), w = (int)(i & 1023);
        const float* bb = (tt == 0) ? bq : (tt == 1 ? bk : bv);
        pb[i] = bb[w];
    }
}

// ---------------- QKV GEMM (f32 compute, bf16 out) ----------------
__global__ __launch_bounds__(256) void k_qkv(const float* __restrict__ A,
    const float* __restrict__ Wp, const float* __restrict__ pb,
    bf16* __restrict__ Qout)
{
    __shared__ float As[8][128];
    __shared__ float Bs[8][128];
    int tid = threadIdx.x;
    int m0 = blockIdx.y * 128, n0 = blockIdx.x * 128;
    int tx = tid & 15, ty = tid >> 4;

    float acc[8][8];
#pragma unroll
    for (int i = 0; i < 8; i++)
#pragma unroll
        for (int j = 0; j < 8; j++) acc[i][j] = 0.f;

    for (int k0 = 0; k0 < 1024; k0 += 8) {
#pragma unroll
        for (int e4 = 0; e4 < 4; e4++) {
            int e = tid * 4 + e4;
            int kl = e & 7, ml = e >> 3;
            int kk = k0 + kl;
            As[kl][ml] = A[(size_t)(m0 + ml) * 1024 + kk];
            Bs[kl][ml] = Wp[(size_t)(n0 + ml) * 1024 + kk];
        }
        __syncthreads();
#pragma unroll
        for (int k = 0; k < 8; k++) {
            float a[8], b[8];
#pragma unroll
            for (int i = 0; i < 8; i++) a[i] = As[k][ty + 16 * i];
#pragma unroll
            for (int j = 0; j < 8; j++) b[j] = Bs[k][tx + 16 * j];
#pragma unroll
            for (int i = 0; i < 8; i++)
#pragma unroll
                for (int j = 0; j < 8; j++) acc[i][j] += a[i] * b[j];
        }
        __syncthreads();
    }

#pragma unroll
    for (int i = 0; i < 8; i++) {
        int m = m0 + ty + 16 * i;
        int b = m >> 9, s = m & 511;
#pragma unroll
        for (int j = 0; j < 8; j++) {
            int n = n0 + tx + 16 * j;
            int tt = n >> 10, w = n & 1023, hh = w >> 7, e = w & 127;
            float v = acc[i][j] + pb[n];
            Qout[(size_t)tt * 16777216ull +
                 ((size_t)(b * NHEAD + hh) * S_LEN + s) * HDIM + e] = __float2bfloat16(v);
        }
    }
}

// ---------------- attention: softmax column-weights -> pooled ----------------
__global__ __launch_bounds__(256) void k_attn(const bf16* __restrict__ Q,
    const bf16* __restrict__ K, const bf16* __restrict__ V,
    float* __restrict__ pooled)
{
    int bh = blockIdx.x;
    int b = bh >> 3, h = bh & 7;
    const bf16* Qb = Q + (size_t)bh * S_LEN * HDIM;
    const bf16* Kb = K + (size_t)bh * S_LEN * HDIM;
    const bf16* Vb = V + (size_t)bh * S_LEN * HDIM;

    __shared__ float Qs[16][HDIM];
    __shared__ float Ss[16][S_LEN + 4];
    __shared__ float wsum[S_LEN];

    int tid = threadIdx.x;
    for (int t = tid; t < S_LEN; t += 256) wsum[t] = 0.f;
    const float SC = 0.08838834764831845f;   // 1/sqrt(128)

    for (int rb = 0; rb < 32; rb++) {
        __syncthreads();
        for (int e = tid; e < 16 * HDIM; e += 256) {
            int rr = e >> 7, ee = e & 127;
            Qs[rr][ee] = __bfloat162float(Qb[(size_t)(rb * 16 + rr) * HDIM + ee]);
        }
        __syncthreads();
        float acc0[16], acc1[16];
#pragma unroll
        for (int r = 0; r < 16; r++) { acc0[r] = 0.f; acc1[r] = 0.f; }
        const bf16* k0p = Kb + (size_t)tid * HDIM;
        const bf16* k1p = Kb + (size_t)(tid + 256) * HDIM;
        for (int k = 0; k < HDIM; k += 4) {
            short4 r0 = *(const short4*)(k0p + k);
            short4 r1 = *(const short4*)(k1p + k);
            float k0x = __bfloat162float(*(const bf16*)&r0.x);
            float k0y = __bfloat162float(*(const bf16*)&r0.y);
            float k0z = __bfloat162float(*(const bf16*)&r0.z);
            float k0w = __bfloat162float(*(const bf16*)&r0.w);
            float k1x = __bfloat162float(*(const bf16*)&r1.x);
            float k1y = __bfloat162float(*(const bf16*)&r1.y);
            float k1z = __bfloat162float(*(const bf16*)&r1.z);
            float k1w = __bfloat162float(*(const bf16*)&r1.w);
#pragma unroll
            for (int r = 0; r < 16; r++) {
                float4 q = *(const float4*)&Qs[r][k];
                acc0[r] += q.x * k0x + q.y * k0y + q.z * k0z + q.w * k0w;
                acc1[r] += q.x * k1x + q.y * k1y + q.z * k1z + q.w * k1w;
            }
        }
#pragma unroll
        for (int r = 0; r < 16; r++) {
            Ss[r][tid] = acc0[r];
            Ss[r][tid + 256] = acc1[r];
        }
        __syncthreads();
        {
            int r = tid >> 4, l = tid & 15;
            float m = -1e30f;
            for (int t = l; t < S_LEN; t += 16) m = fmaxf(m, Ss[r][t]);
#pragma unroll
            for (int o = 1; o < 16; o <<= 1) m = fmaxf(m, __shfl_xor(m, o));
            float sum = 0.f;
            for (int t = l; t < S_LEN; t += 16) {
                float p = expf((Ss[r][t] - m) * SC);
                Ss[r][t] = p;
                sum += p;
            }
#pragma unroll
            for (int o = 1; o < 16; o <<= 1) sum += __shfl_xor(sum, o);
            float inv = 1.f / sum;
            for (int t = l; t < S_LEN; t += 16) Ss[r][t] *= inv;
        }
        __syncthreads();
        for (int t = tid; t < S_LEN; t += 256) {
            float s = 0.f;
#pragma unroll
            for (int rr = 0; rr < 16; rr++) s += Ss[rr][t];
            wsum[t] += s;
        }
    }
    __syncthreads();

    if (tid < HDIM) {
        float a = 0.f;
        for (int t = 0; t < S_LEN; t++)
            a += wsum[t] * __bfloat162float(Vb[(size_t)t * HDIM + tid]);
        pooled[(size_t)b * 1024 + h * HDIM + tid] = a * (1.0f / S_LEN);
    }
}

// ---------------- final FC ----------------
__global__ void k_fc(const float* __restrict__ pooled, const float* __restrict__ Wfc,
                     const float* __restrict__ bfc, float* __restrict__ out)
{
    int j = threadIdx.x;
    if (j < 96) {
        int b = j / 3, o = j - b * 3;
        float a = bfc[o];
        for (int k = 0; k < 1024; k++)
            a += pooled[(size_t)b * 1024 + k] * Wfc[(size_t)o * 1024 + k];
        out[j] = a;
    }
}

// ---------------- launch ----------------
extern "C" void kernel_launch(void* const* d_in, const int* in_sizes, int n_in,
                              void* d_out, int out_size, void* d_ws, size_t ws_size,
                              hipStream_t stream)
{
    const int*   x     = (const int*)d_in[0];
    const float* emb   = (const float*)d_in[1];
    const float* Wih0f = (const float*)d_in[2];
    const float* Whh0f = (const float*)d_in[3];
    const float* bih0f = (const float*)d_in[4];
    const float* bhh0f = (const float*)d_in[5];
    const float* Wih0b = (const float*)d_in[6];
    const float* Whh0b = (const float*)d_in[7];
    const float* bih0b = (const float*)d_in[8];
    const float* bhh0b = (const float*)d_in[9];
    const float* Wih1f = (const float*)d_in[10];
    const float* Whh1f = (const float*)d_in[11];
    const float* bih1f = (const float*)d_in[12];
    const float* bhh1f = (const float*)d_in[13];
    const float* Wih1b = (const float*)d_in[14];
    const float* Whh1b = (const float*)d_in[15];
    const float* bih1b = (const float*)d_in[16];
    const float* bhh1b = (const float*)d_in[17];
    const float* Wq    = (const float*)d_in[18];
    const float* bq    = (const float*)d_in[19];
    const float* Wk    = (const float*)d_in[20];
    const float* bk    = (const float*)d_in[21];
    const float* Wv    = (const float*)d_in[22];
    const float* bv    = (const float*)d_in[23];
    const float* Wfc   = (const float*)d_in[24];
    const float* bfc   = (const float*)d_in[25];

    float* ws     = (float*)d_ws;
    float* xgc    = ws + OFF_XGC;
    float* hcat0  = ws + OFF_HCAT0;
    float* hcat1  = ws + OFF_HCAT1;
    float* h0     = ws + OFF_H0;
    float* Wp     = ws + OFF_WP;
    float* pb     = ws + OFF_PB;
    float* cT     = ws + OFF_CT;
    float* hG     = ws + OFF_HG;
    float* pooled = ws + OFF_POOL;
    unsigned int* bar = (unsigned int*)(ws + OFF_BAR);
    bf16*  Qbf    = (bf16*)ws;                 // aliases xgc+hcat0 (dead by then)
    bf16*  Kbf    = Qbf + 16777216ull;
    bf16*  Vbf    = Qbf + 33554432ull;

    dim3 blk(256);

    hipMemsetAsync(bar, 0, 4096, stream);      // once per launch; tgt monotone after
    k_embed<<<BATCH * S_LEN, 128, 0, stream>>>(x, emb, h0);
    k_pack<<<12288, 256, 0, stream>>>(Wq, Wk, Wv, bq, bk, bv, Wp, pb);

    // ---- layer 0 ----
    for (int c = 0; c < NCH; c++) {
        k_xgc<<<dim3(16, 16, 2), blk, 0, stream>>>(h0, DIM, Wih0f, Wih0b,
            bih0f, bhh0f, bih0b, bhh0b, xgc, DIM, c * CH);
        k_chunk<<<256, 512, 0, stream>>>(xgc, Whh0f, Whh0b, hG, cT, hcat0,
                                         bar, c * CH, 0 * S_LEN + c * CH);
    }
    // ---- layer 1 ----
    for (int c = 0; c < NCH; c++) {
        k_xgc<<<dim3(16, 16, 2), blk, 0, stream>>>(hcat0, 1024, Wih1f, Wih1b,
            bih1f, bhh1f, bih1b, bhh1b, xgc, 1024, c * CH);
        k_chunk<<<256, 512, 0, stream>>>(xgc, Whh1f, Whh1b, hG, cT, hcat1,
                                         bar, c * CH, 1 * S_LEN + c * CH);
    }

    // ---- attention ----
    k_qkv<<<dim3(24, 128), blk, 0, stream>>>(hcat1, Wp, pb, Qbf);
    k_attn<<<256, blk, 0, stream>>>(Qbf, Kbf, Vbf, pooled);
    k_fc<<<1, 128, 0, stream>>>(pooled, Wfc, bfc, (float*)d_out);
}

// Round 6
// 42852.936 us; speedup vs baseline: 1.4365x; 1.4365x over previous
//
#include <hip/hip_runtime.h>
#include <hip/hip_bf16.h>
#include <math.h>

#define S_LEN 512
#define BATCH 32
#define HID   512
#define G4    2048   // 4*H
#define DIM   300
#define NHEAD 8
#define HDIM  128
#define CH    64     // timesteps per xg chunk
#define NCH   8

typedef __hip_bfloat16 bf16;
typedef unsigned long long u64;

// ---------------- workspace layout (float offsets) ----------------
#define OFF_XGC   0ull          //  8,388,608 f  [2 dir][64 slot][2048 n][32 b]
#define OFF_HCAT0 8388608ull    // 16,777,216 f  [32 b][512 s][1024]
#define OFF_HCAT1 25165824ull   // 16,777,216 f  (h0 [16384][300] aliases)
#define OFF_H0    25165824ull
#define OFF_WP    41943040ull   //  3,145,728 f
#define OFF_PB    45088768ull   //      3,072 f
#define OFF_CT    45091840ull   //     32,768 f  [(dir*512+u)*32 + b]
#define OFF_HGA   45124608ull   //     65,536 f = 32,768 u64  [gid(8)][b_local(8)][u(512)]
#define OFF_POOL  45190144ull   //     32,768 f

// ---------------- embedding gather ----------------
__global__ void k_embed(const int* __restrict__ x, const float* __restrict__ emb,
                        float* __restrict__ h0)
{
    int p = blockIdx.x;                 // p = b*512 + s
    int row = x[p];
    const float* src = emb + (size_t)row * DIM;
    float* dst = h0 + (size_t)p * DIM;
    for (int d = threadIdx.x; d < DIM; d += blockDim.x) dst[d] = src[d];
}

// ---------------- chunk input-projection GEMM ----------------
__global__ __launch_bounds__(256) void k_xgc(const float* __restrict__ A, int lda,
    const float* __restrict__ Wf, const float* __restrict__ Wb,
    const float* __restrict__ bihf, const float* __restrict__ bhhf,
    const float* __restrict__ bihb, const float* __restrict__ bhhb,
    float* __restrict__ xgc, int K, int c64)
{
    __shared__ float As[8][128];
    __shared__ float Bs[8][128];
    int tid = threadIdx.x;
    int dir = blockIdx.z;
    int m0 = blockIdx.y * 128, n0 = blockIdx.x * 128;
    const float* W  = dir ? Wb : Wf;
    const float* b1 = dir ? bihb : bihf;
    const float* b2 = dir ? bhhb : bhhf;
    int tx = tid & 15, ty = tid >> 4;

    float acc[8][8];
#pragma unroll
    for (int i = 0; i < 8; i++)
#pragma unroll
        for (int j = 0; j < 8; j++) acc[i][j] = 0.f;

    for (int k0 = 0; k0 < K; k0 += 8) {
#pragma unroll
        for (int e4 = 0; e4 < 4; e4++) {
            int e = tid * 4 + e4;
            int kl = e & 7, ml = e >> 3;
            int kk = k0 + kl;
            int m = m0 + ml;
            int slot = m >> 5, bb = m & 31;
            int s = dir ? (S_LEN - 1 - c64 - slot) : (c64 + slot);
            As[kl][ml] = (kk < K) ? A[((size_t)bb * S_LEN + s) * lda + kk] : 0.f;
            Bs[kl][ml] = (kk < K) ? W[(size_t)(n0 + ml) * K + kk] : 0.f;
        }
        __syncthreads();
#pragma unroll
        for (int k = 0; k < 8; k++) {
            float a[8], b[8];
#pragma unroll
            for (int i = 0; i < 8; i++) a[i] = As[k][ty + 16 * i];
#pragma unroll
            for (int j = 0; j < 8; j++) b[j] = Bs[k][tx + 16 * j];
#pragma unroll
            for (int i = 0; i < 8; i++)
#pragma unroll
                for (int j = 0; j < 8; j++) acc[i][j] += a[i] * b[j];
        }
        __syncthreads();
    }

#pragma unroll
    for (int i = 0; i < 8; i++) {
        int m = m0 + ty + 16 * i;
        int slot = m >> 5, bb = m & 31;
#pragma unroll
        for (int j = 0; j < 8; j++) {
            int n = n0 + tx + 16 * j;
            xgc[(((size_t)dir * CH + slot) * G4 + n) * BATCH + bb] =
                acc[i][j] + b1[n] + b2[n];
        }
    }
}

// ---------------- persistent recurrence: weights in registers, tagged-h exchange ----
// 256 WGs = ublk(32) x gid(8); gid = dir*4+bgrp.  WG: 16 units x 4 gates, 8 batches.
// 512 thr: ks=tid&31, rgrp=tid>>5.  Weights: 4x4 float4 = 64 VGPR, loaded once.
// h exchange: seqlock-style u64 {tag(hi32), f32(lo32)} via RELAXED agent atomics.
// No fences, no barriers: the tag and the value travel in the same atomic word.
__global__ __launch_bounds__(512) void k_chunk(const float* __restrict__ xgc,
    const float* __restrict__ Whh_f, const float* __restrict__ Whh_b,
    u64* __restrict__ hGa, float* __restrict__ cT, float* __restrict__ hcat,
    int c64, int tbase)
{
    __shared__ float Hs[8 * 512];        // [b_local][k]
    __shared__ float gbuf[64][8];        // [row_id][b_local]

    int bid = blockIdx.x;
    int gid = bid & 7;                   // dir*4 + bgrp
    int dir = (gid >> 2) & 1;
    int bgrp = gid & 3;
    int ublk = bid >> 3;                 // 0..31
    const float* Whh = dir ? Whh_b : Whh_f;

    int tid = threadIdx.x;
    int ks = tid & 31;
    int rgrp = tid >> 5;                 // 0..15

    // ---- weights -> registers (coalesced: lanes stride 16B) ----
    float4 w[4][4];
#pragma unroll
    for (int r = 0; r < 4; ++r) {
        int row_id = rgrp * 4 + r;                 // 0..63 ; g = row>>4, ul = row&15
        int g = row_id >> 4, ul = row_id & 15;
        const float* wrow = Whh + (size_t)(g * HID + ublk * 16 + ul) * HID;
#pragma unroll
        for (int q = 0; q < 4; ++q)
            w[r][q] = *(const float4*)(wrow + q * 128 + ks * 4);
    }

    // ---- consumer ids ----
    int bload = tid >> 6;                // 0..7 local batch row
    int l = tid & 63;

    // ---- finisher state (tid<128): (u_local, bl) ----
    int u_local = tid >> 3, bl = tid & 7;
    int b_glob = bgrp * 8 + bl;
    int u_glob = ublk * 16 + u_local;
    size_t ci = ((size_t)dir * HID + u_glob) * BATCH + b_glob;
    float c_reg = 0.f;
    if (tid < 128 && c64 > 0) c_reg = cT[ci];

    for (int i = 0; i < CH; ++i) {
        int tt = c64 + i;
        int gstep = tbase + i;           // global step 0..1023
        int s_cur = dir ? (S_LEN - 1 - tt) : tt;

        // ---- stage h(t-1): tagged atomic words -> LDS ----
        if (tt > 0) {
            unsigned tgt = (unsigned)gstep;   // written by gstep-1 with tag gstep
            const u64* src = hGa + ((size_t)gid * 8 + bload) * 512;
            u64 v[8];
#pragma unroll
            for (int j = 0; j < 8; ++j)
                v[j] = __hip_atomic_load(src + l + 64 * j,
                          __ATOMIC_RELAXED, __HIP_MEMORY_SCOPE_AGENT);
#pragma unroll
            for (int j = 0; j < 8; ++j) {
                while ((unsigned)(v[j] >> 32) != tgt) {
                    __builtin_amdgcn_s_sleep(2);
                    v[j] = __hip_atomic_load(src + l + 64 * j,
                              __ATOMIC_RELAXED, __HIP_MEMORY_SCOPE_AGENT);
                }
                Hs[bload * 512 + l + 64 * j] = __uint_as_float((unsigned)v[j]);
            }
        }
        __syncthreads();

        if (tt > 0) {
            float p[32];
#pragma unroll
            for (int j = 0; j < 32; ++j) p[j] = 0.f;
#pragma unroll
            for (int b = 0; b < 8; ++b) {
                const float4* hb = (const float4*)&Hs[b * 512 + ks * 4];
                float4 h0 = hb[0], h1 = hb[32], h2 = hb[64], h3 = hb[96];
#pragma unroll
                for (int r = 0; r < 4; ++r) {
                    p[r * 8 + b] +=
                        w[r][0].x*h0.x + w[r][0].y*h0.y + w[r][0].z*h0.z + w[r][0].w*h0.w +
                        w[r][1].x*h1.x + w[r][1].y*h1.y + w[r][1].z*h1.z + w[r][1].w*h1.w +
                        w[r][2].x*h2.x + w[r][2].y*h2.y + w[r][2].z*h2.z + w[r][2].w*h2.w +
                        w[r][3].x*h3.x + w[r][3].y*h3.y + w[r][3].z*h3.z + w[r][3].w*h3.w;
                }
            }
            // tournament reduce over the 32 ks lanes: 31 shfl, lane -> 1 sum
#pragma unroll
            for (int st = 0; st < 5; ++st) {
                int m = 1 << st;
                int cnt = 16 >> st;
                bool hi = (ks & m) != 0;
#pragma unroll
                for (int j = 0; j < cnt; ++j) {
                    float send = hi ? p[j] : p[j + cnt];
                    float recv = __shfl_xor(send, m);
                    float keep = hi ? p[j + cnt] : p[j];
                    p[j] = keep + recv;
                }
            }
            // lane ks holds sum for partial index brev5(ks) = r*8+b
            int idx = ((ks & 1) << 4) | ((ks & 2) << 2) | (ks & 4) |
                      ((ks & 8) >> 2) | ((ks & 16) >> 4);
            gbuf[rgrp * 4 + (idx >> 3)][idx & 7] = p[0];
        }
        __syncthreads();

        // ---- finisher: gates -> c,h ; publish tagged h ----
        if (tid < 128) {
            float r0 = 0.f, r1 = 0.f, r2 = 0.f, r3 = 0.f;
            if (tt > 0) {
                r0 = gbuf[0 * 16 + u_local][bl];
                r1 = gbuf[1 * 16 + u_local][bl];
                r2 = gbuf[2 * 16 + u_local][bl];
                r3 = gbuf[3 * 16 + u_local][bl];
            }
            size_t xb = (((size_t)dir * CH + i) * G4) * BATCH + b_glob;
            float gi = r0 + xgc[xb + (size_t)(0 * HID + u_glob) * BATCH];
            float gf = r1 + xgc[xb + (size_t)(1 * HID + u_glob) * BATCH];
            float gg = r2 + xgc[xb + (size_t)(2 * HID + u_glob) * BATCH];
            float go = r3 + xgc[xb + (size_t)(3 * HID + u_glob) * BATCH];
            float si = 1.f / (1.f + expf(-gi));
            float sf = 1.f / (1.f + expf(-gf));
            float so = 1.f / (1.f + expf(-go));
            float cn = sf * c_reg + si * tanhf(gg);
            float hn = so * tanhf(cn);
            c_reg = cn;
            u64 pkt = ((u64)(unsigned)(gstep + 1) << 32) | (u64)__float_as_uint(hn);
            __hip_atomic_store(&hGa[((size_t)gid * 8 + bl) * 512 + u_glob], pkt,
                               __ATOMIC_RELAXED, __HIP_MEMORY_SCOPE_AGENT);
            hcat[((size_t)b_glob * S_LEN + s_cur) * 1024 + dir * HID + u_glob] = hn;
        }
        __syncthreads();   // Hs reuse guard for next step
    }
    if (tid < 128) cT[ci] = c_reg;
}

// ---------------- pack Wq/Wk/Wv -> Wp[3072][1024] + packed bias ----------------
__global__ void k_pack(const float* __restrict__ Wq, const float* __restrict__ Wk,
                       const float* __restrict__ Wv, const float* __restrict__ bq,
                       const float* __restrict__ bk, const float* __restrict__ bv,
                       float* __restrict__ Wp, float* __restrict__ pb)
{
    size_t i = (size_t)blockIdx.x * 256 + threadIdx.x;
    if (i < 3ull * 1024 * 1024) {
        int tt = (int)(i >> 20);
        int w  = (int)(i & 1048575);
        int n  = w >> 10;      // h*128+e
        int d  = w & 1023;
        int hh = n >> 7, e = n & 127;
        const float* W = (tt == 0) ? Wq : (tt == 1 ? Wk : Wv);
        Wp[i] = W[((size_t)hh * 1024 + d) * 128 + e];
    }
    if (i < 3072) {
        int tt = (int)(i >> 10), w = (int)(i & 1023);
        const float* bb = (tt == 0) ? bq : (tt == 1 ? bk : bv);
        pb[i] = bb[w];
    }
}

// ---------------- QKV GEMM (f32 compute, bf16 out) ----------------
__global__ __launch_bounds__(256) void k_qkv(const float* __restrict__ A,
    const float* __restrict__ Wp, const float* __restrict__ pb,
    bf16* __restrict__ Qout)
{
    __shared__ float As[8][128];
    __shared__ float Bs[8][128];
    int tid = threadIdx.x;
    int m0 = blockIdx.y * 128, n0 = blockIdx.x * 128;
    int tx = tid & 15, ty = tid >> 4;

    float acc[8][8];
#pragma unroll
    for (int i = 0; i < 8; i++)
#pragma unroll
        for (int j = 0; j < 8; j++) acc[i][j] = 0.f;

    for (int k0 = 0; k0 < 1024; k0 += 8) {
#pragma unroll
        for (int e4 = 0; e4 < 4; e4++) {
            int e = tid * 4 + e4;
            int kl = e & 7, ml = e >> 3;
            int kk = k0 + kl;
            As[kl][ml] = A[(size_t)(m0 + ml) * 1024 + kk];
            Bs[kl][ml] = Wp[(size_t)(n0 + ml) * 1024 + kk];
        }
        __syncthreads();
#pragma unroll
        for (int k = 0; k < 8; k++) {
            float a[8], b[8];
#pragma unroll
            for (int i = 0; i < 8; i++) a[i] = As[k][ty + 16 * i];
#pragma unroll
            for (int j = 0; j < 8; j++) b[j] = Bs[k][tx + 16 * j];
#pragma unroll
            for (int i = 0; i < 8; i++)
#pragma unroll
                for (int j = 0; j < 8; j++) acc[i][j] += a[i] * b[j];
        }
        __syncthreads();
    }

#pragma unroll
    for (int i = 0; i < 8; i++) {
        int m = m0 + ty + 16 * i;
        int b = m >> 9, s = m & 511;
#pragma unroll
        for (int j = 0; j < 8; j++) {
            int n = n0 + tx + 16 * j;
            int tt = n >> 10, w = n & 1023, hh = w >> 7, e = w & 127;
            float v = acc[i][j] + pb[n];
            Qout[(size_t)tt * 16777216ull +
                 ((size_t)(b * NHEAD + hh) * S_LEN + s) * HDIM + e] = __float2bfloat16(v);
        }
    }
}

// ---------------- attention: softmax column-weights -> pooled ----------------
__global__ __launch_bounds__(256) void k_attn(const bf16* __restrict__ Q,
    const bf16* __restrict__ K, const bf16* __restrict__ V,
    float* __restrict__ pooled)
{
    int bh = blockIdx.x;
    int b = bh >> 3, h = bh & 7;
    const bf16* Qb = Q + (size_t)bh * S_LEN * HDIM;
    const bf16* Kb = K + (size_t)bh * S_LEN * HDIM;
    const bf16* Vb = V + (size_t)bh * S_LEN * HDIM;

    __shared__ float Qs[16][HDIM];
    __shared__ float Ss[16][S_LEN + 4];
    __shared__ float wsum[S_LEN];

    int tid = threadIdx.x;
    for (int t = tid; t < S_LEN; t += 256) wsum[t] = 0.f;
    const float SC = 0.08838834764831845f;   // 1/sqrt(128)

    for (int rb = 0; rb < 32; rb++) {
        __syncthreads();
        for (int e = tid; e < 16 * HDIM; e += 256) {
            int rr = e >> 7, ee = e & 127;
            Qs[rr][ee] = __bfloat162float(Qb[(size_t)(rb * 16 + rr) * HDIM + ee]);
        }
        __syncthreads();
        float acc0[16], acc1[16];
#pragma unroll
        for (int r = 0; r < 16; r++) { acc0[r] = 0.f; acc1[r] = 0.f; }
        const bf16* k0p = Kb + (size_t)tid * HDIM;
        const bf16* k1p = Kb + (size_t)(tid + 256) * HDIM;
        for (int k = 0; k < HDIM; k += 4) {
            short4 r0 = *(const short4*)(k0p + k);
            short4 r1 = *(const short4*)(k1p + k);
            float k0x = __bfloat162float(*(const bf16*)&r0.x);
            float k0y = __bfloat162float(*(const bf16*)&r0.y);
            float k0z = __bfloat162float(*(const bf16*)&r0.z);
            float k0w = __bfloat162float(*(const bf16*)&r0.w);
            float k1x = __bfloat162float(*(const bf16*)&r1.x);
            float k1y = __bfloat162float(*(const bf16*)&r1.y);
            float k1z = __bfloat162float(*(const bf16*)&r1.z);
            float k1w = __bfloat162float(*(const bf16*)&r1.w);
#pragma unroll
            for (int r = 0; r < 16; r++) {
                float4 q = *(const float4*)&Qs[r][k];
                acc0[r] += q.x * k0x + q.y * k0y + q.z * k0z + q.w * k0w;
                acc1[r] += q.x * k1x + q.y * k1y + q.z * k1z + q.w * k1w;
            }
        }
#pragma unroll
        for (int r = 0; r < 16; r++) {
            Ss[r][tid] = acc0[r];
            Ss[r][tid + 256] = acc1[r];
        }
        __syncthreads();
        {
            int r = tid >> 4, l = tid & 15;
            float m = -1e30f;
            for (int t = l; t < S_LEN; t += 16) m = fmaxf(m, Ss[r][t]);
#pragma unroll
            for (int o = 1; o < 16; o <<= 1) m = fmaxf(m, __shfl_xor(m, o));
            float sum = 0.f;
            for (int t = l; t < S_LEN; t += 16) {
                float p = expf((Ss[r][t] - m) * SC);
                Ss[r][t] = p;
                sum += p;
            }
#pragma unroll
            for (int o = 1; o < 16; o <<= 1) sum += __shfl_xor(sum, o);
            float inv = 1.f / sum;
            for (int t = l; t < S_LEN; t += 16) Ss[r][t] *= inv;
        }
        __syncthreads();
        for (int t = tid; t < S_LEN; t += 256) {
            float s = 0.f;
#pragma unroll
            for (int rr = 0; rr < 16; rr++) s += Ss[rr][t];
            wsum[t] += s;
        }
    }
    __syncthreads();

    if (tid < HDIM) {
        float a = 0.f;
        for (int t = 0; t < S_LEN; t++)
            a += wsum[t] * __bfloat162float(Vb[(size_t)t * HDIM + tid]);
        pooled[(size_t)b * 1024 + h * HDIM + tid] = a * (1.0f / S_LEN);
    }
}

// ---------------- final FC ----------------
__global__ void k_fc(const float* __restrict__ pooled, const float* __restrict__ Wfc,
                     const float* __restrict__ bfc, float* __restrict__ out)
{
    int j = threadIdx.x;
    if (j < 96) {
        int b = j / 3, o = j - b * 3;
        float a = bfc[o];
        for (int k = 0; k < 1024; k++)
            a += pooled[(size_t)b * 1024 + k] * Wfc[(size_t)o * 1024 + k];
        out[j] = a;
    }
}

// ---------------- launch ----------------
extern "C" void kernel_launch(void* const* d_in, const int* in_sizes, int n_in,
                              void* d_out, int out_size, void* d_ws, size_t ws_size,
                              hipStream_t stream)
{
    const int*   x     = (const int*)d_in[0];
    const float* emb   = (const float*)d_in[1];
    const float* Wih0f = (const float*)d_in[2];
    const float* Whh0f = (const float*)d_in[3];
    const float* bih0f = (const float*)d_in[4];
    const float* bhh0f = (const float*)d_in[5];
    const float* Wih0b = (const float*)d_in[6];
    const float* Whh0b = (const float*)d_in[7];
    const float* bih0b = (const float*)d_in[8];
    const float* bhh0b = (const float*)d_in[9];
    const float* Wih1f = (const float*)d_in[10];
    const float* Whh1f = (const float*)d_in[11];
    const float* bih1f = (const float*)d_in[12];
    const float* bhh1f = (const float*)d_in[13];
    const float* Wih1b = (const float*)d_in[14];
    const float* Whh1b = (const float*)d_in[15];
    const float* bih1b = (const float*)d_in[16];
    const float* bhh1b = (const float*)d_in[17];
    const float* Wq    = (const float*)d_in[18];
    const float* bq    = (const float*)d_in[19];
    const float* Wk    = (const float*)d_in[20];
    const float* bk    = (const float*)d_in[21];
    const float* Wv    = (const float*)d_in[22];
    const float* bv    = (const float*)d_in[23];
    const float* Wfc   = (const float*)d_in[24];
    const float* bfc   = (const float*)d_in[25];

    float* ws     = (float*)d_ws;
    float* xgc    = ws + OFF_XGC;
    float* hcat0  = ws + OFF_HCAT0;
    float* hcat1  = ws + OFF_HCAT1;
    float* h0     = ws + OFF_H0;
    float* Wp     = ws + OFF_WP;
    float* pb     = ws + OFF_PB;
    float* cT     = ws + OFF_CT;
    u64*   hGa    = (u64*)(ws + OFF_HGA);
    float* pooled = ws + OFF_POOL;
    bf16*  Qbf    = (bf16*)ws;                 // aliases xgc+hcat0 (dead by then)
    bf16*  Kbf    = Qbf + 16777216ull;
    bf16*  Vbf    = Qbf + 33554432ull;

    dim3 blk(256);

    k_embed<<<BATCH * S_LEN, 128, 0, stream>>>(x, emb, h0);
    k_pack<<<12288, 256, 0, stream>>>(Wq, Wk, Wv, bq, bk, bv, Wp, pb);

    // ---- layer 0 ----
    for (int c = 0; c < NCH; c++) {
        k_xgc<<<dim3(16, 16, 2), blk, 0, stream>>>(h0, DIM, Wih0f, Wih0b,
            bih0f, bhh0f, bih0b, bhh0b, xgc, DIM, c * CH);
        k_chunk<<<256, 512, 0, stream>>>(xgc, Whh0f, Whh0b, hGa, cT, hcat0,
                                         c * CH, 0 * S_LEN + c * CH);
    }
    // ---- layer 1 ----
    for (int c = 0; c < NCH; c++) {
        k_xgc<<<dim3(16, 16, 2), blk, 0, stream>>>(hcat0, 1024, Wih1f, Wih1b,
            bih1f, bhh1f, bih1b, bhh1b, xgc, 1024, c * CH);
        k_chunk<<<256, 512, 0, stream>>>(xgc, Whh1f, Whh1b, hGa, cT, hcat1,
                                         c * CH, 1 * S_LEN + c * CH);
    }

    // ---- attention ----
    k_qkv<<<dim3(24, 128), blk, 0, stream>>>(hcat1, Wp, pb, Qbf);
    k_attn<<<256, blk, 0, stream>>>(Qbf, Kbf, Vbf, pooled);
    k_fc<<<1, 128, 0, stream>>>(pooled, Wfc, bfc, (float*)d_out);
}